// Round 8
// baseline (704.473 us; speedup 1.0000x reference)
//
#include <hip/hip_runtime.h>
#include <hip/hip_bf16.h>
#include <math.h>

// Problem constants (fixed by setup_inputs)
#define BB 4
#define TPP 4
#define TFF 2
#define NIMG (BB*TPP)   // 16
#define NF (BB*TFF)     // 8

typedef __attribute__((ext_vector_type(8))) short bf16x8;
typedef __attribute__((ext_vector_type(4))) float f32x4;
#define MFMA16(a,b,c) __builtin_amdgcn_mfma_f32_16x16x32_bf16(a,b,c,0,0,0)

// async global->LDS copy, 16B per lane; LDS dest = wave-uniform base + lane*16
#define GLL(gaddr, laddr) __builtin_amdgcn_global_load_lds( \
    (const __attribute__((address_space(1))) void*)(gaddr), \
    (__attribute__((address_space(3))) void*)(laddr), 16, 0, 0)

__device__ __forceinline__ unsigned short f2bf(float x) {
    __hip_bfloat16 h = __float2bfloat16(x);
    return *reinterpret_cast<unsigned short*>(&h);
}
__device__ __forceinline__ float bf2f(unsigned short u) {
    unsigned int v = ((unsigned int)u) << 16;
    return __uint_as_float(v);
}

// ---------------------------------------------------------------------------
// Tiny kernel: replicate _interp_indices on device + mark needed past frames.
// ---------------------------------------------------------------------------
__global__ void idx_kernel(const int* __restrict__ pci, const int* __restrict__ fci,
                           int* __restrict__ idx, int* __restrict__ needed)
{
    if (threadIdx.x == 0 && blockIdx.x == 0) {
        for (int n = 0; n < BB*TPP; n++) needed[n] = 0;
        for (int i = 0; i < BB; i++) {
            needed[i*TPP + TPP-1] = 1;              // f1 frame always needed
            int p_pos = TPP - 2;
            for (int j = 0; j < TFF; j++) {
                int f = fci[i*TFF + j];
                while (p_pos >= 0) {
                    if (p_pos == 0 || f < -pci[i*TPP + p_pos - 1]) {
                        idx[i*TFF + j] = p_pos + i*TPP;
                        needed[p_pos + i*TPP] = 1;
                        break;
                    }
                    p_pos--;
                }
            }
        }
    }
}

// ---------------------------------------------------------------------------
// Weight prep: split W[d][c]*scale[d] into bf16 hi/lo, stored in MFMA
// A-fragment order.  Conv A-staging becomes pure GLL.
// ---------------------------------------------------------------------------
template<int C>
__device__ __forceinline__ void wtile_frag(const float* __restrict__ w,
                                           const float* __restrict__ g,
                                           const float* __restrict__ v,
                                           unsigned short* __restrict__ whi,
                                           unsigned short* __restrict__ wlo, int tile)
{
    constexpr int DT = C/16;
    const int ct = tile / DT, dt = tile % DT;
    const int t = threadIdx.x;
    const size_t base = (size_t)tile * 512;
    #pragma unroll
    for (int e = 0; e < 2; e++) {
        int pos = t*2 + e;                 // 0..511
        int lane = pos >> 3, j = pos & 7;
        int m = lane & 15, q = lane >> 4;
        int d = dt*16 + m, c = ct*32 + q*8 + j;
        float sc = g[d] * rsqrtf(v[d] + 1e-5f);
        float x = w[(size_t)d*C + c] * sc;
        unsigned short hi = f2bf(x);
        float lof = x - bf2f(hi);
        whi[base + pos] = hi;
        wlo[base + pos] = f2bf(lof);
    }
}

__global__ __launch_bounds__(256)
void wprep_kernel(const float* w0, const float* g0, const float* b0, const float* m0, const float* v0,
                  unsigned short* whi0, unsigned short* wlo0, float* sh0,
                  const float* w1, const float* g1, const float* b1, const float* m1, const float* v1,
                  unsigned short* whi1, unsigned short* wlo1, float* sh1,
                  const float* w2, const float* g2, const float* b2, const float* m2, const float* v2,
                  unsigned short* whi2, unsigned short* wlo2, float* sh2)
{
    int bid = blockIdx.x;
    if (bid < 32)        wtile_frag<128>(w0, g0, v0, whi0, wlo0, bid);
    else if (bid < 160)  wtile_frag<256>(w1, g1, v1, whi1, wlo1, bid - 32);
    else if (bid < 672)  wtile_frag<512>(w2, g2, v2, whi2, wlo2, bid - 160);
    else {
        for (int i = threadIdx.x; i < 896; i += 256) {
            if (i < 128)      { int d=i;     float sc=g0[d]*rsqrtf(v0[d]+1e-5f); sh0[d]=b0[d]-m0[d]*sc; }
            else if (i < 384) { int d=i-128; float sc=g1[d]*rsqrtf(v1[d]+1e-5f); sh1[d]=b1[d]-m1[d]*sc; }
            else              { int d=i-384; float sc=g2[d]*rsqrtf(v2[d]+1e-5f); sh2[d]=b2[d]-m2[d]*sc; }
        }
    }
}

// ---------------------------------------------------------------------------
// MFMA conv (bf16x3 split): 128(d) x 128(p) per block, K-tile 32. (round-4)
// ---------------------------------------------------------------------------
template<int C, int HW>
__device__ __forceinline__ void conv_mfma_tile(
    const float* __restrict__ x,
    const unsigned short* __restrict__ whi,
    const unsigned short* __restrict__ wlo,
    const float* __restrict__ sh,
    float* __restrict__ pf,
    int n, int dblk, int pblk,
    unsigned short* __restrict__ Ahi, unsigned short* __restrict__ Alo,
    unsigned short* __restrict__ Bhi, unsigned short* __restrict__ Blo)
{
    constexpr int DT = C/16;
    const int tid  = threadIdx.x;
    const int lane = tid & 63;
    const int wv   = tid >> 6;
    const int d0 = dblk*128, p0 = pblk*128;
    const float* xn = x + (size_t)n * C * HW;
    const int wdt = (wv >> 1) * 4;
    const int wpt = (wv & 1) * 4;
    const int kb  = (lane >> 4) * 8;
    const int pn  = lane & 15;

    f32x4 acc[4][4];
    #pragma unroll
    for (int i = 0; i < 4; i++)
        #pragma unroll
        for (int j = 0; j < 4; j++)
            acc[i][j] = f32x4{0.f, 0.f, 0.f, 0.f};

    for (int ct = 0; ct < C/32; ct++) {
        __syncthreads();
        {
            const size_t gb = ((size_t)ct * DT + dblk*8) * 512 + (size_t)lane*8;
            const unsigned short* ghi = whi + gb;
            const unsigned short* glo = wlo + gb;
            GLL(ghi + (size_t)wv*512,     Ahi + wv*512);
            GLL(ghi + (size_t)(wv+4)*512, Ahi + (wv+4)*512);
            GLL(glo + (size_t)wv*512,     Alo + wv*512);
            GLL(glo + (size_t)(wv+4)*512, Alo + (wv+4)*512);
        }
        #pragma unroll
        for (int e = 0; e < 2; e++) {
            int pt = e*4 + (tid >> 6);
            int pp = p0 + pt*16 + pn;
            int pc = pp < HW ? pp : HW-1;
            const float* src = xn + (size_t)(ct*32 + kb) * HW + pc;
            bf16x8 h8, l8;
            #pragma unroll
            for (int j = 0; j < 8; j++) {
                float xv = src[(size_t)j * HW];
                unsigned short hi = f2bf(xv);
                h8[j] = (short)hi;
                l8[j] = (short)f2bf(xv - bf2f(hi));
            }
            int slot = pt*64 + lane;
            *(bf16x8*)(Bhi + slot*8) = h8;
            *(bf16x8*)(Blo + slot*8) = l8;
        }
        __syncthreads();
        bf16x8 bh[4], bl[4];
        #pragma unroll
        for (int j = 0; j < 4; j++) {
            bh[j] = *(const bf16x8*)(Bhi + (wpt+j)*512 + lane*8);
            bl[j] = *(const bf16x8*)(Blo + (wpt+j)*512 + lane*8);
        }
        #pragma unroll
        for (int i = 0; i < 4; i++) {
            bf16x8 ah = *(const bf16x8*)(Ahi + (wdt+i)*512 + lane*8);
            bf16x8 al = *(const bf16x8*)(Alo + (wdt+i)*512 + lane*8);
            #pragma unroll
            for (int j = 0; j < 4; j++) {
                acc[i][j] = MFMA16(ah, bh[j], acc[i][j]);
                acc[i][j] = MFMA16(al, bh[j], acc[i][j]);
                acc[i][j] = MFMA16(ah, bl[j], acc[i][j]);
            }
        }
    }

    const int rowq = (lane >> 4) * 4;
    #pragma unroll
    for (int i = 0; i < 4; i++) {
        #pragma unroll
        for (int r = 0; r < 4; r++) {
            int d = d0 + (wdt+i)*16 + rowq + r;
            float shd = sh[d];
            float* dst = pf + ((size_t)n * C + d) * HW;
            #pragma unroll
            for (int j = 0; j < 4; j++) {
                int p = p0 + (wpt+j)*16 + pn;
                float y = acc[i][j][r] + shd;
                float o = y / (1.f + __expf(-y));
                if (p < HW) dst[p] = o;
            }
        }
    }
}

__global__ __launch_bounds__(256, 2)
void conv_all(const float* x0, const unsigned short* whi0, const unsigned short* wlo0,
              const float* sh0, float* pf0,
              const float* x1, const unsigned short* whi1, const unsigned short* wlo1,
              const float* sh1, float* pf1,
              const float* x2, const unsigned short* whi2, const unsigned short* wlo2,
              const float* sh2, float* pf2,
              const int* __restrict__ needed)
{
    __shared__ __align__(16) unsigned short Ahi[8*512];
    __shared__ __align__(16) unsigned short Alo[8*512];
    __shared__ __align__(16) unsigned short Bhi[8*512];
    __shared__ __align__(16) unsigned short Blo[8*512];
    const int bid = blockIdx.x;
    if (bid < 256) {
        int n = bid >> 4, d = (bid >> 2) & 3, p = bid & 3;
        if (!needed[n]) return;
        conv_mfma_tile<512, 400>(x2, whi2, wlo2, sh2, pf2, n, d, p, Ahi, Alo, Bhi, Blo);
    } else if (bid < 672) {
        int rel = bid - 256;
        int n = rel / 26, rem = rel % 26;
        int d = rem / 13, p = rem % 13;
        if (!needed[n]) return;
        conv_mfma_tile<256, 1600>(x1, whi1, wlo1, sh1, pf1, n, d, p, Ahi, Alo, Bhi, Blo);
    } else {
        int rel = bid - 672;
        int n = rel / 50, p = rel % 50;
        if (!needed[n]) return;
        conv_mfma_tile<128, 6400>(x0, whi0, wlo0, sh0, pf0, n, 0, p, Ahi, Alo, Bhi, Blo);
    }
}

// ---------------------------------------------------------------------------
// Corr phase 1 (v4): partial sums per (b, c, chunk).
// 384 threads = 6 waves = (2 pixel-halves) x (3 FIXED ky-triples).
// Each lane processes QG consecutive quads (L0:4=16px, L1:2=8px, L2:1=4px;
// all give exactly 5 groups/row), so one window read of 8*STEP+4*QG floats
// feeds 9kx * 4*QG px * 2 frames FMAs -> uniform 24 FMA per ds_read_b128
// (3x less LDS traffic than v3's 8 FMA/b128).  Compile-time wave roles
// (round-5/6 lesson: runtime roles spill to scratch).
// ---------------------------------------------------------------------------
template<int C, int H, int W, int STEP, int CHUNKS, int QG>
__device__ __forceinline__ void corr_partial_tile(
    const float* __restrict__ pf, const int* __restrict__ idx,
    float* __restrict__ part_out, int c, int b, int chunk, float* __restrict__ smem)
{
    constexpr int PAD  = 4 * STEP;
    constexpr int PW   = W + 2*PAD;
    constexpr int HW   = H * W;
    constexpr int HC   = H / CHUNKS;          // rows per chunk
    constexpr int ROWS = HC + 2*PAD;          // staged padded rows
    constexpr int PQ   = PW / 4;              // float4s per padded row
    constexpr int GPR  = W / (4*QG);          // groups per row (=5 all levels)
    constexpr int GROUPS = HC * GPR;          // groups in this chunk
    constexpr int GPH  = GROUPS / 2;          // groups per pixel-half
    constexpr int ITERS = (GPH + 63) / 64;
    constexpr int WINF  = 8*STEP + 4*QG;      // window floats per (group,ky)
    constexpr int WIN4  = WINF / 4;

    float* f1s  = smem;                       // ROWS*PW plane
    float* part = smem + ROWS*PW;             // [2][2][81]

    const int tid  = threadIdx.x;
    const int lane = tid & 63;
    const int wave = tid >> 6;
    const int ph   = wave / 3;                // pixel half
    const int kys  = wave % 3;                // fixed ky triple

    const int r0 = chunk * HC;
    const float* f1  = pf + ((size_t)(b*TPP + TPP-1) * C + c) * HW;
    const float* f2a = pf + ((size_t)idx[b*TFF + 0] * C + c) * HW + (size_t)r0 * W;
    const float* f2b = pf + ((size_t)idx[b*TFF + 1] * C + c) * HW + (size_t)r0 * W;

    // stage padded rows [r0-PAD, r0+HC+PAD) as float4
    for (int s = tid; s < ROWS*PQ; s += 384) {
        int lr = s / PQ;
        int q  = s - lr*PQ;
        int y  = r0 + lr - PAD;
        int x4 = q*4 - PAD;
        float4 v = make_float4(0.f, 0.f, 0.f, 0.f);
        if (y >= 0 && y < H && x4 >= 0 && x4 < W)
            v = *(const float4*)(f1 + (size_t)y*W + x4);
        *(float4*)&f1s[lr*PW + q*4] = v;
    }
    __syncthreads();

    float acc[2][3][9];
    #pragma unroll
    for (int f = 0; f < 2; f++)
        #pragma unroll
        for (int j = 0; j < 3; j++)
            #pragma unroll
            for (int k = 0; k < 9; k++) acc[f][j][k] = 0.f;

    #pragma unroll 1
    for (int it = 0; it < ITERS; it++) {
        int g = ph*GPH + it*64 + lane;
        if (g < (ph+1)*GPH) {
            int hl  = g / GPR;                // row within chunk
            int col = (g - hl*GPR) * (4*QG);  // start pixel within row
            int p4  = hl*W + col;
            float4 fa[QG], fb[QG];
            #pragma unroll
            for (int qi = 0; qi < QG; qi++) {
                fa[qi] = *(const float4*)(f2a + p4 + qi*4);
                fb[qi] = *(const float4*)(f2b + p4 + qi*4);
            }
            #pragma unroll
            for (int j = 0; j < 3; j++) {
                int ky = kys*3 + j;
                const float* row = &f1s[(hl + PAD + (ky-4)*STEP) * PW + col];
                float win[WINF];
                #pragma unroll
                for (int t = 0; t < WIN4; t++)
                    *(float4*)&win[t*4] = *(const float4*)&row[t*4];
                #pragma unroll
                for (int kx = 0; kx < 9; kx++) {
                    float sa = acc[0][j][kx];
                    float sb = acc[1][j][kx];
                    #pragma unroll
                    for (int qi = 0; qi < QG; qi++) {
                        const float* wp = &win[kx*STEP + qi*4];
                        sa = fmaf(wp[0], fa[qi].x, sa);
                        sa = fmaf(wp[1], fa[qi].y, sa);
                        sa = fmaf(wp[2], fa[qi].z, sa);
                        sa = fmaf(wp[3], fa[qi].w, sa);
                        sb = fmaf(wp[0], fb[qi].x, sb);
                        sb = fmaf(wp[1], fb[qi].y, sb);
                        sb = fmaf(wp[2], fb[qi].z, sb);
                        sb = fmaf(wp[3], fb[qi].w, sb);
                    }
                    acc[0][j][kx] = sa;
                    acc[1][j][kx] = sb;
                }
            }
        }
    }

    // per-wave butterfly; lane 0 writes its (half, frame, ky-triple) rows
    #pragma unroll
    for (int f = 0; f < 2; f++)
        #pragma unroll
        for (int j = 0; j < 3; j++)
            #pragma unroll
            for (int kx = 0; kx < 9; kx++) {
                float v = acc[f][j][kx];
                v += __shfl_xor(v, 32);
                v += __shfl_xor(v, 16);
                v += __shfl_xor(v, 8);
                v += __shfl_xor(v, 4);
                v += __shfl_xor(v, 2);
                v += __shfl_xor(v, 1);
                if (lane == 0) part[(ph*2 + f)*81 + (kys*3 + j)*9 + kx] = v;
            }
    __syncthreads();
    // combine halves, write partial vector to global P
    float* pb = part_out + ((((size_t)b*C + c)*CHUNKS + chunk)*2) * 81;
    if (tid < 162) {
        int f = tid / 81, k = tid % 81;
        pb[(size_t)f*81 + k] = part[(0*2 + f)*81 + k] + part[(1*2 + f)*81 + k];
    }
}

__global__ __launch_bounds__(384)
void corr_partial(const float* __restrict__ pf0, const float* __restrict__ pf1,
                  const float* __restrict__ pf2, const int* __restrict__ idx,
                  float* __restrict__ P0, float* __restrict__ P1, float* __restrict__ P2)
{
    extern __shared__ float smem[];
    const int bid = blockIdx.x;
    if (bid < 2048) {                         // level 0: 4b x 128c x 4chunk
        int b = bid >> 9, c = (bid >> 2) & 127, ch = bid & 3;
        corr_partial_tile<128, 80, 80, 4, 4, 4>(pf0, idx, P0, c, b, ch, smem);
    } else if (bid < 4096) {                  // level 1: 4b x 256c x 2chunk
        int r = bid - 2048;
        int b = r >> 9, c = (r >> 1) & 255, ch = r & 1;
        corr_partial_tile<256, 40, 40, 2, 2, 2>(pf1, idx, P1, c, b, ch, smem);
    } else {                                  // level 2: 4b x 512c x 1chunk
        int r = bid - 4096;
        int b = r >> 9, c = r & 511;
        corr_partial_tile<512, 20, 20, 1, 1, 1>(pf2, idx, P2, c, b, 0, smem);
    }
}

// ---------------------------------------------------------------------------
// Corr phase 2: sum chunks + softmax(81) + mlp dot.  128 thr = 2 waves = 2
// frames; one block per (level, b, c).
// ---------------------------------------------------------------------------
template<int C, int CHUNKS>
__device__ __forceinline__ void fin_tile(const float* __restrict__ part,
                                         const float* __restrict__ mlp,
                                         float* __restrict__ out, int b, int c)
{
    const int tid  = threadIdx.x;
    const int lane = tid & 63;
    const int f    = tid >> 6;
    const float* p = part + ((((size_t)b*C + c)*CHUNKS)*2 + f) * 81;
    float v0 = 0.f, v1 = 0.f;
    #pragma unroll
    for (int ch = 0; ch < CHUNKS; ch++) {
        v0 += p[(size_t)ch*162 + lane];
        if (lane + 64 < 81) v1 += p[(size_t)ch*162 + lane + 64];
    }
    if (lane + 64 >= 81) v1 = -INFINITY;
    float mx = fmaxf(v0, v1);
    #pragma unroll
    for (int m = 32; m; m >>= 1) mx = fmaxf(mx, __shfl_xor(mx, m));
    float e0 = __expf(v0 - mx);
    float e1 = (lane + 64 < 81) ? __expf(v1 - mx) : 0.f;
    float ssum = e0 + e1;
    float dsum = e0 * mlp[lane] + ((lane + 64 < 81) ? e1 * mlp[lane + 64] : 0.f);
    #pragma unroll
    for (int m = 32; m; m >>= 1) {
        ssum += __shfl_xor(ssum, m);
        dsum += __shfl_xor(dsum, m);
    }
    if (lane == 0) out[(size_t)(b*TFF + f) * C + c] = dsum / ssum;
}

__global__ __launch_bounds__(128)
void corr_fin(const float* __restrict__ P0, const float* __restrict__ P1,
              const float* __restrict__ P2, const float* __restrict__ mlp,
              float* __restrict__ out)
{
    const int bid = blockIdx.x;
    if (bid < 512) {                          // level 0: 4b x 128c
        fin_tile<128, 4>(P0, mlp, out, bid >> 7, bid & 127);
    } else if (bid < 1536) {                  // level 1: 4b x 256c
        int r = bid - 512;
        fin_tile<256, 2>(P1, mlp, out + (size_t)NF*128, r >> 8, r & 255);
    } else {                                  // level 2: 4b x 512c
        int r = bid - 1536;
        fin_tile<512, 1>(P2, mlp, out + (size_t)NF*(128+256), r >> 9, r & 511);
    }
}

// ---------------------------------------------------------------------------
extern "C" void kernel_launch(void* const* d_in, const int* in_sizes, int n_in,
                              void* d_out, int out_size, void* d_ws, size_t ws_size,
                              hipStream_t stream)
{
    const float* feat0 = (const float*)d_in[0];
    const float* w0 = (const float*)d_in[1];
    const float* g0 = (const float*)d_in[2];
    const float* b0 = (const float*)d_in[3];
    const float* m0 = (const float*)d_in[4];
    const float* v0 = (const float*)d_in[5];
    const float* feat1 = (const float*)d_in[6];
    const float* w1 = (const float*)d_in[7];
    const float* g1 = (const float*)d_in[8];
    const float* b1 = (const float*)d_in[9];
    const float* m1 = (const float*)d_in[10];
    const float* v1 = (const float*)d_in[11];
    const float* feat2 = (const float*)d_in[12];
    const float* w2 = (const float*)d_in[13];
    const float* g2 = (const float*)d_in[14];
    const float* b2 = (const float*)d_in[15];
    const float* m2 = (const float*)d_in[16];
    const float* v2 = (const float*)d_in[17];
    const float* mlp = (const float*)d_in[18];
    const int* pci = (const int*)d_in[19];
    const int* fci = (const int*)d_in[20];

    float* out = (float*)d_out;

    // workspace layout
    char* base = (char*)d_ws;
    int* idxp    = (int*)base;                 // 8
    int* neededp = idxp + 8;                   // 16
    float* sh0 = (float*)(base + 256);         // 128
    float* sh1 = sh0 + 128;                    // 256
    float* sh2 = sh1 + 256;                    // 512
    unsigned short* whi0 = (unsigned short*)(sh2 + 512);
    unsigned short* wlo0 = whi0 + 128*128;
    unsigned short* whi1 = wlo0 + 128*128;
    unsigned short* wlo1 = whi1 + 256*256;
    unsigned short* whi2 = wlo1 + 256*256;
    unsigned short* wlo2 = whi2 + 512*512;
    float* pf0 = (float*)(wlo2 + 512*512);
    float* pf1 = pf0 + (size_t)NIMG * 128 * 6400;
    float* pf2 = pf1 + (size_t)NIMG * 256 * 1600;
    float* P0  = pf2 + (size_t)NIMG * 512 * 400;
    float* P1  = P0 + (size_t)BB * 128 * 4 * 2 * 81;
    float* P2  = P1 + (size_t)BB * 256 * 2 * 2 * 81;

    idx_kernel<<<1, 64, 0, stream>>>(pci, fci, idxp, neededp);
    wprep_kernel<<<673, 256, 0, stream>>>(
        w0, g0, b0, m0, v0, whi0, wlo0, sh0,
        w1, g1, b1, m1, v1, whi1, wlo1, sh1,
        w2, g2, b2, m2, v2, whi2, wlo2, sh2);

    // all conv levels, one dispatch (L2's K=512 blocks first)
    conv_all<<<1472, 256, 0, stream>>>(
        feat0, whi0, wlo0, sh0, pf0,
        feat1, whi1, wlo1, sh1, pf1,
        feat2, whi2, wlo2, sh2, pf2,
        neededp);

    // corr phase 1: partial sums (dynamic LDS = L0 staged chunk + combine buf)
    corr_partial<<<6144, 384, (52*112 + 324) * sizeof(float), stream>>>(
        pf0, pf1, pf2, idxp, P0, P1, P2);

    // corr phase 2: chunk-sum + softmax + mlp dot
    corr_fin<<<3584, 128, 0, stream>>>(P0, P1, P2, mlp, out);
}

// Round 9
// 389.056 us; speedup vs baseline: 1.8107x; 1.8107x over previous
//
#include <hip/hip_runtime.h>
#include <hip/hip_bf16.h>
#include <math.h>

// Problem constants (fixed by setup_inputs)
#define BB 4
#define TPP 4
#define TFF 2
#define NIMG (BB*TPP)   // 16
#define NF (BB*TFF)     // 8

typedef __attribute__((ext_vector_type(8))) short bf16x8;
typedef __attribute__((ext_vector_type(4))) float f32x4;
#define MFMA16(a,b,c) __builtin_amdgcn_mfma_f32_16x16x32_bf16(a,b,c,0,0,0)

// async global->LDS copy, 16B per lane; LDS dest = wave-uniform base + lane*16
#define GLL(gaddr, laddr) __builtin_amdgcn_global_load_lds( \
    (const __attribute__((address_space(1))) void*)(gaddr), \
    (__attribute__((address_space(3))) void*)(laddr), 16, 0, 0)

__device__ __forceinline__ unsigned short f2bf(float x) {
    __hip_bfloat16 h = __float2bfloat16(x);
    return *reinterpret_cast<unsigned short*>(&h);
}
__device__ __forceinline__ float bf2f(unsigned short u) {
    unsigned int v = ((unsigned int)u) << 16;
    return __uint_as_float(v);
}

// ---------------------------------------------------------------------------
// Tiny kernel: replicate _interp_indices on device + mark needed past frames.
// ---------------------------------------------------------------------------
__global__ void idx_kernel(const int* __restrict__ pci, const int* __restrict__ fci,
                           int* __restrict__ idx, int* __restrict__ needed)
{
    if (threadIdx.x == 0 && blockIdx.x == 0) {
        for (int n = 0; n < BB*TPP; n++) needed[n] = 0;
        for (int i = 0; i < BB; i++) {
            needed[i*TPP + TPP-1] = 1;              // f1 frame always needed
            int p_pos = TPP - 2;
            for (int j = 0; j < TFF; j++) {
                int f = fci[i*TFF + j];
                while (p_pos >= 0) {
                    if (p_pos == 0 || f < -pci[i*TPP + p_pos - 1]) {
                        idx[i*TFF + j] = p_pos + i*TPP;
                        needed[p_pos + i*TPP] = 1;
                        break;
                    }
                    p_pos--;
                }
            }
        }
    }
}

// ---------------------------------------------------------------------------
// Weight prep: split W[d][c]*scale[d] into bf16 hi/lo, stored in MFMA
// A-fragment order.  Conv A-staging becomes pure GLL.
// ---------------------------------------------------------------------------
template<int C>
__device__ __forceinline__ void wtile_frag(const float* __restrict__ w,
                                           const float* __restrict__ g,
                                           const float* __restrict__ v,
                                           unsigned short* __restrict__ whi,
                                           unsigned short* __restrict__ wlo, int tile)
{
    constexpr int DT = C/16;
    const int ct = tile / DT, dt = tile % DT;
    const int t = threadIdx.x;
    const size_t base = (size_t)tile * 512;
    #pragma unroll
    for (int e = 0; e < 2; e++) {
        int pos = t*2 + e;                 // 0..511
        int lane = pos >> 3, j = pos & 7;
        int m = lane & 15, q = lane >> 4;
        int d = dt*16 + m, c = ct*32 + q*8 + j;
        float sc = g[d] * rsqrtf(v[d] + 1e-5f);
        float x = w[(size_t)d*C + c] * sc;
        unsigned short hi = f2bf(x);
        float lof = x - bf2f(hi);
        whi[base + pos] = hi;
        wlo[base + pos] = f2bf(lof);
    }
}

__global__ __launch_bounds__(256)
void wprep_kernel(const float* w0, const float* g0, const float* b0, const float* m0, const float* v0,
                  unsigned short* whi0, unsigned short* wlo0, float* sh0,
                  const float* w1, const float* g1, const float* b1, const float* m1, const float* v1,
                  unsigned short* whi1, unsigned short* wlo1, float* sh1,
                  const float* w2, const float* g2, const float* b2, const float* m2, const float* v2,
                  unsigned short* whi2, unsigned short* wlo2, float* sh2)
{
    int bid = blockIdx.x;
    if (bid < 32)        wtile_frag<128>(w0, g0, v0, whi0, wlo0, bid);
    else if (bid < 160)  wtile_frag<256>(w1, g1, v1, whi1, wlo1, bid - 32);
    else if (bid < 672)  wtile_frag<512>(w2, g2, v2, whi2, wlo2, bid - 160);
    else {
        for (int i = threadIdx.x; i < 896; i += 256) {
            if (i < 128)      { int d=i;     float sc=g0[d]*rsqrtf(v0[d]+1e-5f); sh0[d]=b0[d]-m0[d]*sc; }
            else if (i < 384) { int d=i-128; float sc=g1[d]*rsqrtf(v1[d]+1e-5f); sh1[d]=b1[d]-m1[d]*sc; }
            else              { int d=i-384; float sc=g2[d]*rsqrtf(v2[d]+1e-5f); sh2[d]=b2[d]-m2[d]*sc; }
        }
    }
}

// ---------------------------------------------------------------------------
// MFMA conv (bf16x3 split): 128(d) x 128(p) per block, K-tile 32. (round-4)
// ---------------------------------------------------------------------------
template<int C, int HW>
__device__ __forceinline__ void conv_mfma_tile(
    const float* __restrict__ x,
    const unsigned short* __restrict__ whi,
    const unsigned short* __restrict__ wlo,
    const float* __restrict__ sh,
    float* __restrict__ pf,
    int n, int dblk, int pblk,
    unsigned short* __restrict__ Ahi, unsigned short* __restrict__ Alo,
    unsigned short* __restrict__ Bhi, unsigned short* __restrict__ Blo)
{
    constexpr int DT = C/16;
    const int tid  = threadIdx.x;
    const int lane = tid & 63;
    const int wv   = tid >> 6;
    const int d0 = dblk*128, p0 = pblk*128;
    const float* xn = x + (size_t)n * C * HW;
    const int wdt = (wv >> 1) * 4;
    const int wpt = (wv & 1) * 4;
    const int kb  = (lane >> 4) * 8;
    const int pn  = lane & 15;

    f32x4 acc[4][4];
    #pragma unroll
    for (int i = 0; i < 4; i++)
        #pragma unroll
        for (int j = 0; j < 4; j++)
            acc[i][j] = f32x4{0.f, 0.f, 0.f, 0.f};

    for (int ct = 0; ct < C/32; ct++) {
        __syncthreads();
        {
            const size_t gb = ((size_t)ct * DT + dblk*8) * 512 + (size_t)lane*8;
            const unsigned short* ghi = whi + gb;
            const unsigned short* glo = wlo + gb;
            GLL(ghi + (size_t)wv*512,     Ahi + wv*512);
            GLL(ghi + (size_t)(wv+4)*512, Ahi + (wv+4)*512);
            GLL(glo + (size_t)wv*512,     Alo + wv*512);
            GLL(glo + (size_t)(wv+4)*512, Alo + (wv+4)*512);
        }
        #pragma unroll
        for (int e = 0; e < 2; e++) {
            int pt = e*4 + (tid >> 6);
            int pp = p0 + pt*16 + pn;
            int pc = pp < HW ? pp : HW-1;
            const float* src = xn + (size_t)(ct*32 + kb) * HW + pc;
            bf16x8 h8, l8;
            #pragma unroll
            for (int j = 0; j < 8; j++) {
                float xv = src[(size_t)j * HW];
                unsigned short hi = f2bf(xv);
                h8[j] = (short)hi;
                l8[j] = (short)f2bf(xv - bf2f(hi));
            }
            int slot = pt*64 + lane;
            *(bf16x8*)(Bhi + slot*8) = h8;
            *(bf16x8*)(Blo + slot*8) = l8;
        }
        __syncthreads();
        bf16x8 bh[4], bl[4];
        #pragma unroll
        for (int j = 0; j < 4; j++) {
            bh[j] = *(const bf16x8*)(Bhi + (wpt+j)*512 + lane*8);
            bl[j] = *(const bf16x8*)(Blo + (wpt+j)*512 + lane*8);
        }
        #pragma unroll
        for (int i = 0; i < 4; i++) {
            bf16x8 ah = *(const bf16x8*)(Ahi + (wdt+i)*512 + lane*8);
            bf16x8 al = *(const bf16x8*)(Alo + (wdt+i)*512 + lane*8);
            #pragma unroll
            for (int j = 0; j < 4; j++) {
                acc[i][j] = MFMA16(ah, bh[j], acc[i][j]);
                acc[i][j] = MFMA16(al, bh[j], acc[i][j]);
                acc[i][j] = MFMA16(ah, bl[j], acc[i][j]);
            }
        }
    }

    const int rowq = (lane >> 4) * 4;
    #pragma unroll
    for (int i = 0; i < 4; i++) {
        #pragma unroll
        for (int r = 0; r < 4; r++) {
            int d = d0 + (wdt+i)*16 + rowq + r;
            float shd = sh[d];
            float* dst = pf + ((size_t)n * C + d) * HW;
            #pragma unroll
            for (int j = 0; j < 4; j++) {
                int p = p0 + (wpt+j)*16 + pn;
                float y = acc[i][j][r] + shd;
                float o = y / (1.f + __expf(-y));
                if (p < HW) dst[p] = o;
            }
        }
    }
}

__global__ __launch_bounds__(256, 2)
void conv_all(const float* x0, const unsigned short* whi0, const unsigned short* wlo0,
              const float* sh0, float* pf0,
              const float* x1, const unsigned short* whi1, const unsigned short* wlo1,
              const float* sh1, float* pf1,
              const float* x2, const unsigned short* whi2, const unsigned short* wlo2,
              const float* sh2, float* pf2,
              const int* __restrict__ needed)
{
    __shared__ __align__(16) unsigned short Ahi[8*512];
    __shared__ __align__(16) unsigned short Alo[8*512];
    __shared__ __align__(16) unsigned short Bhi[8*512];
    __shared__ __align__(16) unsigned short Blo[8*512];
    const int bid = blockIdx.x;
    if (bid < 256) {
        int n = bid >> 4, d = (bid >> 2) & 3, p = bid & 3;
        if (!needed[n]) return;
        conv_mfma_tile<512, 400>(x2, whi2, wlo2, sh2, pf2, n, d, p, Ahi, Alo, Bhi, Blo);
    } else if (bid < 672) {
        int rel = bid - 256;
        int n = rel / 26, rem = rel % 26;
        int d = rem / 13, p = rem % 13;
        if (!needed[n]) return;
        conv_mfma_tile<256, 1600>(x1, whi1, wlo1, sh1, pf1, n, d, p, Ahi, Alo, Bhi, Blo);
    } else {
        int rel = bid - 672;
        int n = rel / 50, p = rel % 50;
        if (!needed[n]) return;
        conv_mfma_tile<128, 6400>(x0, whi0, wlo0, sh0, pf0, n, 0, p, Ahi, Alo, Bhi, Blo);
    }
}

// ---------------------------------------------------------------------------
// Fused corr (v5): one block per (b, c), full padded f1 plane in LDS,
// in-block softmax + mlp dot (no partial buffers, no second dispatch).
// 384 threads = 6 waves = (2 FRAMES) x (3 FIXED ky-triples): each wave
// covers ALL pixels of its frame.  Each lane processes QG consecutive quads
// (L0:4, L1:2, L2:1 -> 5 groups/row at every level), so one window read of
// 8*STEP+4*QG floats feeds 9kx*4QG px FMAs = uniform 12 FMA per b128.
// Register budget: acc[3][9]=27 + win<=48 + fa 16 = 91 floats -- below the
// proven no-spill level (r7: 98).  Round-8 lesson: both-frames-per-wave at
// QG=4 needs 134 floats -> scratch spill at the compiler's 128-VGPR cap.
// ---------------------------------------------------------------------------
template<int C, int H, int W, int STEP, int QG>
__device__ __forceinline__ void corr_tile(
    const float* __restrict__ pf, const int* __restrict__ idx,
    const float* __restrict__ mlp, float* __restrict__ out,
    int c, int b, float* __restrict__ smem)
{
    constexpr int PAD  = 4 * STEP;
    constexpr int PW   = W + 2*PAD;
    constexpr int PH   = H + 2*PAD;
    constexpr int HW   = H * W;
    constexpr int PQ   = PW / 4;              // float4s per padded row
    constexpr int GPR  = W / (4*QG);          // groups per row (=5 all levels)
    constexpr int GROUPS = H * GPR;           // groups in the plane
    constexpr int ITERS  = (GROUPS + 63) / 64;
    constexpr int WINF   = 8*STEP + 4*QG;     // window floats per (group,ky)
    constexpr int WIN4   = WINF / 4;

    float* f1s  = smem;                       // PH*PW padded plane
    float* part = smem + PH*PW;               // [2][81]

    const int tid  = threadIdx.x;
    const int lane = tid & 63;
    const int wave = tid >> 6;
    const int fr   = wave / 3;                // frame (0/1)
    const int kys  = wave % 3;                // fixed ky triple

    const float* f1 = pf + ((size_t)(b*TPP + TPP-1) * C + c) * HW;
    const float* f2 = pf + ((size_t)idx[b*TFF + fr] * C + c) * HW;

    // stage full padded f1 plane as float4
    for (int s = tid; s < PH*PQ; s += 384) {
        int lr = s / PQ;                      // compile-time divisor
        int q  = s - lr*PQ;
        int y  = lr - PAD;
        int x4 = q*4 - PAD;
        float4 v = make_float4(0.f, 0.f, 0.f, 0.f);
        if (y >= 0 && y < H && x4 >= 0 && x4 < W)
            v = *(const float4*)(f1 + (size_t)y*W + x4);
        *(float4*)&f1s[lr*PW + q*4] = v;
    }
    __syncthreads();

    float acc[3][9];
    #pragma unroll
    for (int j = 0; j < 3; j++)
        #pragma unroll
        for (int k = 0; k < 9; k++) acc[j][k] = 0.f;

    #pragma unroll 1
    for (int it = 0; it < ITERS; it++) {
        int g = it*64 + lane;
        if (g < GROUPS) {
            int hl  = g / GPR;                // image row (compile-time div)
            int col = (g - hl*GPR) * (4*QG);  // start pixel within row
            const float* src = f2 + (size_t)hl*W + col;
            float4 fa[QG];
            #pragma unroll
            for (int qi = 0; qi < QG; qi++)
                fa[qi] = *(const float4*)(src + qi*4);
            #pragma unroll
            for (int j = 0; j < 3; j++) {
                int ky = kys*3 + j;
                const float* row = &f1s[(hl + PAD + (ky-4)*STEP) * PW + col];
                float win[WINF];
                #pragma unroll
                for (int t = 0; t < WIN4; t++)
                    *(float4*)&win[t*4] = *(const float4*)&row[t*4];
                #pragma unroll
                for (int kx = 0; kx < 9; kx++) {
                    float s = acc[j][kx];
                    #pragma unroll
                    for (int qi = 0; qi < QG; qi++) {
                        const float* wp = &win[kx*STEP + qi*4];
                        s = fmaf(wp[0], fa[qi].x, s);
                        s = fmaf(wp[1], fa[qi].y, s);
                        s = fmaf(wp[2], fa[qi].z, s);
                        s = fmaf(wp[3], fa[qi].w, s);
                    }
                    acc[j][kx] = s;
                }
            }
        }
    }

    // per-wave butterfly; lane 0 writes its (frame, ky-triple) rows
    #pragma unroll
    for (int j = 0; j < 3; j++)
        #pragma unroll
        for (int kx = 0; kx < 9; kx++) {
            float v = acc[j][kx];
            v += __shfl_xor(v, 32);
            v += __shfl_xor(v, 16);
            v += __shfl_xor(v, 8);
            v += __shfl_xor(v, 4);
            v += __shfl_xor(v, 2);
            v += __shfl_xor(v, 1);
            if (lane == 0) part[fr*81 + (kys*3 + j)*9 + kx] = v;
        }
    __syncthreads();

    // softmax over 81 + dot with mlp weights; wave f handles frame f
    if (tid < 128) {
        int f = wave;
        float v0 = part[f*81 + lane];
        float v1 = (lane + 64 < 81) ? part[f*81 + lane + 64] : -INFINITY;
        float mx = fmaxf(v0, v1);
        #pragma unroll
        for (int m = 32; m; m >>= 1) mx = fmaxf(mx, __shfl_xor(mx, m));
        float e0 = __expf(v0 - mx);
        float e1 = (lane + 64 < 81) ? __expf(v1 - mx) : 0.f;
        float ssum = e0 + e1;
        float dsum = e0 * mlp[lane] + ((lane + 64 < 81) ? e1 * mlp[lane + 64] : 0.f);
        #pragma unroll
        for (int m = 32; m; m >>= 1) {
            ssum += __shfl_xor(ssum, m);
            dsum += __shfl_xor(dsum, m);
        }
        if (lane == 0) out[(size_t)(b*TFF + f) * C + c] = dsum / ssum;
    }
}

__global__ __launch_bounds__(384)
void corr_all(const float* __restrict__ pf0, const float* __restrict__ pf1,
              const float* __restrict__ pf2, const int* __restrict__ idx,
              const float* __restrict__ mlp, float* __restrict__ out)
{
    extern __shared__ float smem[];
    const int bid = blockIdx.x;
    if (bid < 512) {                          // level 0 (heaviest first)
        corr_tile<128, 80, 80, 4, 4>(pf0, idx, mlp, out, bid & 127, bid >> 7, smem);
    } else if (bid < 1536) {                  // level 1
        int r = bid - 512;
        corr_tile<256, 40, 40, 2, 2>(pf1, idx, mlp, out + (size_t)NF*128, r & 255, r >> 8, smem);
    } else {                                  // level 2
        int r = bid - 1536;
        corr_tile<512, 20, 20, 1, 1>(pf2, idx, mlp, out + (size_t)NF*(128+256), r & 511, r >> 9, smem);
    }
}

// ---------------------------------------------------------------------------
extern "C" void kernel_launch(void* const* d_in, const int* in_sizes, int n_in,
                              void* d_out, int out_size, void* d_ws, size_t ws_size,
                              hipStream_t stream)
{
    const float* feat0 = (const float*)d_in[0];
    const float* w0 = (const float*)d_in[1];
    const float* g0 = (const float*)d_in[2];
    const float* b0 = (const float*)d_in[3];
    const float* m0 = (const float*)d_in[4];
    const float* v0 = (const float*)d_in[5];
    const float* feat1 = (const float*)d_in[6];
    const float* w1 = (const float*)d_in[7];
    const float* g1 = (const float*)d_in[8];
    const float* b1 = (const float*)d_in[9];
    const float* m1 = (const float*)d_in[10];
    const float* v1 = (const float*)d_in[11];
    const float* feat2 = (const float*)d_in[12];
    const float* w2 = (const float*)d_in[13];
    const float* g2 = (const float*)d_in[14];
    const float* b2 = (const float*)d_in[15];
    const float* m2 = (const float*)d_in[16];
    const float* v2 = (const float*)d_in[17];
    const float* mlp = (const float*)d_in[18];
    const int* pci = (const int*)d_in[19];
    const int* fci = (const int*)d_in[20];

    float* out = (float*)d_out;

    // workspace layout
    char* base = (char*)d_ws;
    int* idxp    = (int*)base;                 // 8
    int* neededp = idxp + 8;                   // 16
    float* sh0 = (float*)(base + 256);         // 128
    float* sh1 = sh0 + 128;                    // 256
    float* sh2 = sh1 + 256;                    // 512
    unsigned short* whi0 = (unsigned short*)(sh2 + 512);
    unsigned short* wlo0 = whi0 + 128*128;
    unsigned short* whi1 = wlo0 + 128*128;
    unsigned short* wlo1 = whi1 + 256*256;
    unsigned short* whi2 = wlo1 + 256*256;
    unsigned short* wlo2 = whi2 + 512*512;
    float* pf0 = (float*)(wlo2 + 512*512);
    float* pf1 = pf0 + (size_t)NIMG * 128 * 6400;
    float* pf2 = pf1 + (size_t)NIMG * 256 * 1600;

    idx_kernel<<<1, 64, 0, stream>>>(pci, fci, idxp, neededp);
    wprep_kernel<<<673, 256, 0, stream>>>(
        w0, g0, b0, m0, v0, whi0, wlo0, sh0,
        w1, g1, b1, m1, v1, whi1, wlo1, sh1,
        w2, g2, b2, m2, v2, whi2, wlo2, sh2);

    // all conv levels, one dispatch (L2's K=512 blocks first)
    conv_all<<<1472, 256, 0, stream>>>(
        feat0, whi0, wlo0, sh0, pf0,
        feat1, whi1, wlo1, sh1, pf1,
        feat2, whi2, wlo2, sh2, pf2,
        neededp);

    // fused corr + softmax + mlp: one dispatch, one block per (b,c)
    // dyn LDS = L0 padded plane (112x112) + part[2][81]
    corr_all<<<3584, 384, (112*112 + 176) * sizeof(float), stream>>>(
        pf0, pf1, pf2, idxp, mlp, out);
}